// Round 13
// baseline (4247.928 us; speedup 1.0000x reference)
//
#include <hip/hip_runtime.h>

#define NB 64    // batch
#define NT 512   // timesteps
#define NI 256   // input dim
#define NH 1024  // hidden dim
#define NO 256   // output dim
#define NWG 256  // workgroups in cooperative kernel
#define NU 4     // hidden units per WG (NWG*NU == NH)
#define NR 16    // gate rows per WG = 4*NU
#define NGRP 16  // producer groups
#define GSZ 16   // WGs per group

typedef __attribute__((ext_vector_type(8))) __bf16 bf16x8;
typedef __attribute__((ext_vector_type(8))) unsigned short u16x8;
typedef __attribute__((ext_vector_type(4))) float f32x4;

union FragQ { unsigned long long q[2]; bf16x8 v; };

static __device__ __forceinline__ unsigned short f2bf(float f) {
  unsigned int u = __float_as_uint(f);
  unsigned int r = (u + 0x7fffu + ((u >> 16) & 1u)) >> 16;  // RNE
  return (unsigned short)r;
}

// bar[] layout (u32 words), one 128B line per unit:
//   word (1+g)*32            : group-g arrival counter (monotone)
//   words (17+h)*32 + g      : flag replica for CONSUMER group h, producer g
//                              flag value = #steps group g has published.
// Total 33 lines = 1056 words; zeroed by xpose, overwritten by outproj's y.

// ---------------------------------------------------------------- x transpose
__global__ void __launch_bounds__(256) xpose_kernel(const float* __restrict__ x,
                                                    unsigned short* __restrict__ xbf,
                                                    unsigned int* __restrict__ bar) {
  if (blockIdx.x == 0)
    for (int w = threadIdx.x; w < (1 + NGRP * 2) * 32; w += 256)
      __hip_atomic_store(bar + w, 0u, __ATOMIC_RELAXED, __HIP_MEMORY_SCOPE_AGENT);
  int idx = blockIdx.x * 256 + threadIdx.x;
  const int total = NB * NT * NI / 8;
  for (int e = idx; e < total; e += gridDim.x * 256) {
    int i8 = (e & 31) * 8;      // I/8 = 32 groups per row
    int tb = e >> 5;            // t*NB + b
    int b = tb & (NB - 1);
    int t = tb >> 6;
    const float* src = x + ((b * NT + t) << 8) + i8;
    u16x8 v;
#pragma unroll
    for (int j = 0; j < 8; ++j) v[j] = f2bf(src[j]);
    *(u16x8*)(xbf + e * 8) = v;
  }
}

// ---------------------------------------------------------------- LSTM (coop)
// R10 data path. Sync redesign: NO global barrier. Producer group g's last
// arriver (per-group counter, vmcnt-drained sc1 h-stores) bumps 16 replicated
// flags. Consumer waves poll only their 8 producer flags (replica line of
// their own group) and consume h K-chunks INCREMENTALLY as they land --
// accumulation commutes, so out-of-order is fine. A WG waits only for the
// slowest producer, having already processed every other chunk.
__global__ void __launch_bounds__(512) lstm_kernel(
    const unsigned short* __restrict__ xbf,   // [T][B][I] bf16
    const float* __restrict__ Wih,            // [4H][I]
    const float* __restrict__ Whh,            // [4H][H]
    const float* __restrict__ bih,
    const float* __restrict__ bhh,
    unsigned short* __restrict__ hall,        // [T][B][H] bf16
    unsigned int* __restrict__ bar) {
  __shared__ __align__(16) unsigned short Wh_l[NR * NH];   // 32 KB
  __shared__ __align__(16) unsigned short Wi_l[NR * NI];   // 8 KB
  __shared__ float bias_l[NR];
  __shared__ float zbuf[2][NB][17];                        // pad 17: no conflicts
  __shared__ __align__(16) unsigned short hstage[NB * NU]; // 512 B

  const int tid = threadIdx.x;
  const int u0 = blockIdx.x * NU;
  const int grp = blockIdx.x >> 4;   // this WG's producer group

  // Stage weight slices fp32 -> bf16 into LDS, swizzled: idx ^= (row&7)<<3
  for (int idx = tid; idx < NR * NH; idx += 512) {
    int r = idx >> 10;
    int k = idx & (NH - 1);
    int g = r >> 2, uu = r & 3;
    Wh_l[(r << 10) | (k ^ ((r & 7) << 3))] = f2bf(Whh[(g * NH + u0 + uu) * NH + k]);
  }
  for (int idx = tid; idx < NR * NI; idx += 512) {
    int r = idx >> 8;
    int k = idx & (NI - 1);
    int g = r >> 2, uu = r & 3;
    Wi_l[(r << 8) | (k ^ ((r & 7) << 3))] = f2bf(Wih[(g * NH + u0 + uu) * NI + k]);
  }
  if (tid < NR) {
    int g = tid >> 2, uu = tid & 3;
    bias_l[tid] = bih[g * NH + u0 + uu] + bhh[g * NH + u0 + uu];
  }
  __syncthreads();

  const int wave = tid >> 6;
  const int lane = tid & 63;
  const int lr = lane & 15;   // A row within M-tile / B gate-row / D col
  const int lq = lane >> 4;   // k-subgroup / D row-group
  const int m = wave & 3;     // M tile (16 batches)
  const int kh = wave >> 2;   // K half (h-cols kh*512..+511 = producer groups kh*8..+7)

  const int eb = tid >> 2;    // elementwise batch (threads 0..255)
  const int eu = tid & 3;     // elementwise unit
  float c_state = 0.f;

  const int arow = m * 16 + lr;
  const unsigned short* wi_row = Wi_l + lr * NI;
  const unsigned short* wh_row = Wh_l + lr * NH;
  const int swz = (lr & 7) << 3;

  // Flag word this lane polls: replica line of MY group, producer kh*8+(lane&7)
  unsigned int* const flagw = bar + (17 + grp) * 32 + (kh * 8 + (lane & 7));

#define COMPUTE_AX(T_, AX0, AX1)                                                \
  do {                                                                          \
    AX0 = (f32x4){0.f, 0.f, 0.f, 0.f};                                          \
    AX1 = (f32x4){0.f, 0.f, 0.f, 0.f};                                          \
    const unsigned short* xrow = xbf + ((T_) * NB + arow) * NI + lq * 8;        \
    _Pragma("unroll")                                                           \
    for (int kk2 = 0; kk2 < 2; ++kk2) {                                         \
      int kk = kh * 4 + kk2 * 2;                                                \
      bf16x8 a0 = *(const bf16x8*)(xrow + kk * 32);                             \
      bf16x8 b0 = *(const bf16x8*)(wi_row + ((kk * 32 + lq * 8) ^ swz));        \
      AX0 = __builtin_amdgcn_mfma_f32_16x16x32_bf16(a0, b0, AX0, 0, 0, 0);      \
      bf16x8 a1 = *(const bf16x8*)(xrow + (kk + 1) * 32);                       \
      bf16x8 b1 = *(const bf16x8*)(wi_row + (((kk + 1) * 32 + lq * 8) ^ swz));  \
      AX1 = __builtin_amdgcn_mfma_f32_16x16x32_bf16(a1, b1, AX1, 0, 0, 0);      \
    }                                                                           \
  } while (0)

  f32x4 ax0, ax1;
  COMPUTE_AX(0, ax0, ax1);

  for (int t = 0; t < NT; ++t) {
    f32x4 ah0 = {0.f, 0.f, 0.f, 0.f};
    f32x4 ah1 = {0.f, 0.f, 0.f, 0.f};
    // h contribution, consumed chunk-by-chunk as producer flags land.
    // Chunk g2 (0..7) of this wave = h-cols kh*512 + g2*64 (producer kh*8+g2),
    // = 2 MFMAs. Plain cached loads (L2 amortizes broadcast; validated R10).
    if (t > 0) {
      const unsigned long long* hrow =
          (const unsigned long long*)(hall + ((t - 1) * NB + arow) * NH) + lq * 2;
      unsigned int done = 0;
      while (done != 0xffu) {
        unsigned int f = __hip_atomic_load(flagw, __ATOMIC_RELAXED, __HIP_MEMORY_SCOPE_AGENT);
        unsigned long long bal = __ballot(f >= (unsigned int)t);
        unsigned int newm = ((unsigned int)bal & 0xffu) & ~done;
        if (newm == 0u) { __builtin_amdgcn_s_sleep(1); continue; }
        done |= newm;
        do {
          int g2 = __builtin_ctz(newm);
          newm &= newm - 1u;
          int kk = kh * 16 + g2 * 2;
          FragQ a0, a1;
          a0.q[0] = hrow[kk * 8 + 0];
          a0.q[1] = hrow[kk * 8 + 1];
          a1.q[0] = hrow[kk * 8 + 8];
          a1.q[1] = hrow[kk * 8 + 9];
          bf16x8 b0 = *(const bf16x8*)(wh_row + ((kk * 32 + lq * 8) ^ swz));
          bf16x8 b1 = *(const bf16x8*)(wh_row + (((kk + 1) * 32 + lq * 8) ^ swz));
          ah0 = __builtin_amdgcn_mfma_f32_16x16x32_bf16(a0.v, b0, ah0, 0, 0, 0);
          ah1 = __builtin_amdgcn_mfma_f32_16x16x32_bf16(a1.v, b1, ah1, 0, 0, 0);
        } while (newm);
      }
    }
    f32x4 z4 = (ah0 + ah1) + (ax0 + ax1);
    // D layout: col = lane&15 (gate row), row = (lane>>4)*4 + j (batch)
#pragma unroll
    for (int j = 0; j < 4; ++j)
      zbuf[kh][m * 16 + lq * 4 + j][lr] = z4[j];
    __syncthreads();

    if (tid < 256) {
      float zi = zbuf[0][eb][0 * NU + eu] + zbuf[1][eb][0 * NU + eu] + bias_l[0 * NU + eu];
      float zf = zbuf[0][eb][1 * NU + eu] + zbuf[1][eb][1 * NU + eu] + bias_l[1 * NU + eu];
      float zg = zbuf[0][eb][2 * NU + eu] + zbuf[1][eb][2 * NU + eu] + bias_l[2 * NU + eu];
      float zo = zbuf[0][eb][3 * NU + eu] + zbuf[1][eb][3 * NU + eu] + bias_l[3 * NU + eu];
      float ig = 1.f / (1.f + __expf(-zi));
      float fg = 1.f / (1.f + __expf(-zf));
      float gg = tanhf(zg);
      float og = 1.f / (1.f + __expf(-zo));
      c_state = fg * c_state + ig * gg;
      float hv = og * tanhf(c_state);
      hstage[eb * NU + eu] = f2bf(hv);
    }
    __syncthreads();

    // Wave 0 publishes the WG's h-slice: 64 lanes x 8B, sc1 -> LLC.
    if (wave == 0) {
      unsigned long long hq = *(const unsigned long long*)(hstage + lane * NU);
      __hip_atomic_store((unsigned long long*)(hall + (t * NB + lane) * NH + u0), hq,
                         __ATOMIC_RELAXED, __HIP_MEMORY_SCOPE_AGENT);
    }
    // Arrival: drain wave-0 h-stores (vmcnt), relaxed add to group counter;
    // the group's LAST arriver fans the step-done flag out to all 16 replica
    // lines (fire-and-forget relaxed stores -- consumers see them at LLC).
    if (tid == 0) {
      asm volatile("s_waitcnt vmcnt(0)" ::: "memory");
      unsigned int old = __hip_atomic_fetch_add(bar + (1 + grp) * 32, 1u,
                                                __ATOMIC_RELAXED, __HIP_MEMORY_SCOPE_AGENT);
      if (old == (unsigned int)(t * GSZ + (GSZ - 1))) {
#pragma unroll
        for (int h = 0; h < NGRP; ++h)
          __hip_atomic_store(bar + (17 + h) * 32 + grp, (unsigned int)(t + 1),
                             __ATOMIC_RELAXED, __HIP_MEMORY_SCOPE_AGENT);
      }
    }
    // Next step's x-MFMAs fill the publish->poll gap (h-independent).
    if (t + 1 < NT) COMPUTE_AX(t + 1, ax0, ax1);
  }
#undef COMPUTE_AX
}

// ---------------------------------------------------------------- y = h @ Wout^T + b
__global__ void __launch_bounds__(256) outproj_kernel(
    const unsigned short* __restrict__ hall,  // [T*B][H] bf16
    const float* __restrict__ Wout,           // [O][H]
    const float* __restrict__ bout,           // [O]
    float* __restrict__ y) {                  // [B][T][O] fp32
  __shared__ __align__(16) unsigned short At[64 * 64];
  __shared__ __align__(16) unsigned short Bt[64 * 64];
  const int tid = threadIdx.x;
  const int row0 = blockIdx.x * 64;
  const int col0 = blockIdx.y * 64;
  const int wave = tid >> 6, lane = tid & 63, lr = lane & 15, lq = lane >> 4;
  f32x4 acc[4];
#pragma unroll
  for (int n = 0; n < 4; ++n) acc[n] = (f32x4){0.f, 0.f, 0.f, 0.f};
  const int rr = tid >> 4;
  const int kk4 = (tid & 15) * 4;

  for (int kc = 0; kc < NH / 64; ++kc) {
#pragma unroll
    for (int p = 0; p < 4; ++p) {
      int r = rr + p * 16;
      ushort4 va = *(const ushort4*)(hall + (size_t)(row0 + r) * NH + kc * 64 + kk4);
      *(ushort4*)(At + r * 64 + (kk4 ^ ((r & 7) << 3))) = va;
      float4 vb = *(const float4*)(Wout + (size_t)(col0 + r) * NH + kc * 64 + kk4);
      ushort4 wb;
      wb.x = f2bf(vb.x); wb.y = f2bf(vb.y); wb.z = f2bf(vb.z); wb.w = f2bf(vb.w);
      *(ushort4*)(Bt + r * 64 + (kk4 ^ ((r & 7) << 3))) = wb;
    }
    __syncthreads();
#pragma unroll
    for (int kk = 0; kk < 2; ++kk) {
      int kb = kk * 32 + lq * 8;
      bf16x8 af = *(const bf16x8*)(At + (wave * 16 + lr) * 64 + (kb ^ ((lr & 7) << 3)));
#pragma unroll
      for (int n = 0; n < 4; ++n) {
        bf16x8 bf = *(const bf16x8*)(Bt + (n * 16 + lr) * 64 + (kb ^ ((lr & 7) << 3)));
        acc[n] = __builtin_amdgcn_mfma_f32_16x16x32_bf16(af, bf, acc[n], 0, 0, 0);
      }
    }
    __syncthreads();
  }
#pragma unroll
  for (int n = 0; n < 4; ++n) {
    int o = col0 + n * 16 + lr;
    float bo = bout[o];
#pragma unroll
    for (int j = 0; j < 4; ++j) {
      int r = row0 + wave * 16 + lq * 4 + j;  // r = t*NB + b
      int b = r & (NB - 1);
      int t = r >> 6;
      y[(size_t)((b << 9) | t) * NO + o] = acc[n][j] + bo;
    }
  }
}

// ---------------------------------------------------------------- launch
extern "C" void kernel_launch(void* const* d_in, const int* in_sizes, int n_in,
                              void* d_out, int out_size, void* d_ws, size_t ws_size,
                              hipStream_t stream) {
  const float* x    = (const float*)d_in[0];
  const float* Wih  = (const float*)d_in[1];
  const float* Whh  = (const float*)d_in[2];
  const float* bih  = (const float*)d_in[3];
  const float* bhh  = (const float*)d_in[4];
  const float* Wout = (const float*)d_in[5];
  const float* bout = (const float*)d_in[6];
  float* y = (float*)d_out;

  // ws layout: xbf (16 MB) | hall (64 MB)  => 80 MB needed
  unsigned short* xbf  = (unsigned short*)d_ws;
  unsigned short* hall = xbf + (size_t)NT * NB * NI;
  // Sync words live in d_out[0..1055]: zeroed by xpose_kernel before the
  // coop kernel, fully overwritten by outproj_kernel afterwards.
  unsigned int* bar = (unsigned int*)d_out;

  hipLaunchKernelGGL(xpose_kernel, dim3(1024), dim3(256), 0, stream, x, xbf, bar);

  void* args[7];
  args[0] = (void*)&xbf;
  args[1] = (void*)&Wih;
  args[2] = (void*)&Whh;
  args[3] = (void*)&bih;
  args[4] = (void*)&bhh;
  args[5] = (void*)&hall;
  args[6] = (void*)&bar;
  hipLaunchCooperativeKernel(lstm_kernel, dim3(NWG), dim3(512), args, 0u, stream);

  hipLaunchKernelGGL(outproj_kernel, dim3(512, 4), dim3(256), 0, stream,
                     hall, Wout, bout, y);
}